// Round 4
// baseline (552.693 us; speedup 1.0000x reference)
//
#include <hip/hip_runtime.h>
#include <hip/hip_bf16.h>
#include <cstdint>
#include <cstddef>

#define N_NODES 8192
#define DIN 512
#define DOUT 256
#define CAP 512   // max edges/row buffered; Binom(8192,0.004): mean 32.8, sd 5.7

typedef short bf16x8 __attribute__((ext_vector_type(8)));
typedef float f32x4 __attribute__((ext_vector_type(4)));

__device__ __forceinline__ float bf2f(unsigned short u) {
    union { unsigned int ui; float f; } v; v.ui = ((unsigned int)u) << 16; return v.f;
}
__device__ __forceinline__ unsigned short f2bf(float f) {
    union { float f; unsigned int u; } v; v.f = f;
    unsigned int u = v.u;
    return (unsigned short)((u + 0x7fffu + ((u >> 16) & 1u)) >> 16);  // RNE
}
__device__ __forceinline__ float elu1(float v) { return v > 0.f ? v : (expf(v) - 1.f); }

// -------- kernel 1: h = elu(x) @ W1 + b1   [8192,512]fp32 x [512,256]fp32 -> bf16 h --------
// block tile 64 rows x 64 cols; wave computes 4 m-subtiles of 16x16 (B frag reused 4x)
// mfma_f32_16x16x32_bf16: A[m=lane&15][k=quad*8+j], B[k=quad*8+j][n=lane&15],
// D[row=quad*4+r][col=lane&15]
__global__ __launch_bounds__(256) void gemm_h_kernel(
    const float* __restrict__ x, const float* __restrict__ W1,
    const float* __restrict__ b1, unsigned short* __restrict__ h)
{
    const int tid = threadIdx.x;
    const int wave = tid >> 6, lane = tid & 63;
    const int quad = lane >> 4, r16 = lane & 15;
    const int m0 = (blockIdx.x >> 2) * 64;                 // 128 m-blocks
    const int col = (blockIdx.x & 3) * 64 + wave * 16 + r16;

    f32x4 acc[4] = {{0.f,0.f,0.f,0.f},{0.f,0.f,0.f,0.f},{0.f,0.f,0.f,0.f},{0.f,0.f,0.f,0.f}};

    for (int k0 = 0; k0 < DIN; k0 += 32) {
        const int kbase = k0 + quad * 8;
        bf16x8 bfr;
        #pragma unroll
        for (int j = 0; j < 8; ++j)
            bfr[j] = (short)f2bf(W1[(size_t)(kbase + j) * DOUT + col]);
        #pragma unroll
        for (int r = 0; r < 4; ++r) {
            const float* xrow = x + (size_t)(m0 + r * 16 + r16) * DIN;
            float4 f0 = *(const float4*)(xrow + kbase);
            float4 f1 = *(const float4*)(xrow + kbase + 4);
            bf16x8 af;
            af[0] = (short)f2bf(elu1(f0.x)); af[1] = (short)f2bf(elu1(f0.y));
            af[2] = (short)f2bf(elu1(f0.z)); af[3] = (short)f2bf(elu1(f0.w));
            af[4] = (short)f2bf(elu1(f1.x)); af[5] = (short)f2bf(elu1(f1.y));
            af[6] = (short)f2bf(elu1(f1.z)); af[7] = (short)f2bf(elu1(f1.w));
            acc[r] = __builtin_amdgcn_mfma_f32_16x16x32_bf16(af, bfr, acc[r], 0, 0, 0);
        }
    }
    const float bias = b1[col];
    #pragma unroll
    for (int r = 0; r < 4; ++r)
        #pragma unroll
        for (int rr = 0; rr < 4; ++rr)
            h[(size_t)(m0 + r * 16 + quad * 4 + rr) * DOUT + col] = f2bf(acc[r][rr] + bias);
}

// -------- kernel 2: g1 = h@a1_w + a1_b, g2 = h@a2_w + a2_b  (wave per row) --------
__global__ __launch_bounds__(256) void g12_kernel(
    const unsigned short* __restrict__ h,
    const float* __restrict__ a1w, const float* __restrict__ a1b,
    const float* __restrict__ a2w, const float* __restrict__ a2b,
    float* __restrict__ g1, float* __restrict__ g2)
{
    const int tid = threadIdx.x;
    const int wave = tid >> 6, lane = tid & 63;
    const int i = blockIdx.x * 4 + wave;
    float s1 = 0.f, s2 = 0.f;
    #pragma unroll
    for (int c = 0; c < 4; ++c) {
        int d = lane + c * 64;
        float hv = bf2f(h[(size_t)i * DOUT + d]);
        s1 += hv * a1w[d];
        s2 += hv * a2w[d];
    }
    #pragma unroll
    for (int off = 32; off > 0; off >>= 1) {
        s1 += __shfl_xor(s1, off, 64);
        s2 += __shfl_xor(s2, off, 64);
    }
    if (lane == 0) {
        g1[i] = s1 + a1b[0];
        g2[i] = s2 + a2b[0];
    }
}

// -------- kernel 3: per-row masked softmax + aggregation (block per row) --------
__global__ __launch_bounds__(256) void agg_kernel(
    const float* __restrict__ adj, const unsigned short* __restrict__ h,
    const float* __restrict__ g1, const float* __restrict__ g2,
    float* __restrict__ out)
{
    __shared__ int   eidx[CAP];
    __shared__ float ev[CAP];
    __shared__ float red[256];
    __shared__ int   cnt;

    const int tid = threadIdx.x;
    const int i = blockIdx.x;
    if (tid == 0) cnt = 0;
    __syncthreads();

    const float g2i = g2[i];
    const float* arow = adj + (size_t)i * N_NODES;
    const int jbase = tid * 32;   // 32 columns per thread

    #pragma unroll
    for (int c = 0; c < 8; ++c) {
        uint4 raw = *(const uint4*)(arow + jbase + c * 4);   // 4 fp32
        if (raw.x | raw.y | raw.z | raw.w) {
            unsigned int wv[4] = {raw.x, raw.y, raw.z, raw.w};
            #pragma unroll
            for (int q = 0; q < 4; ++q) {
                if (wv[q]) {
                    int j = jbase + c * 4 + q;
                    union { unsigned int u; float f; } av; av.u = wv[q];
                    float s = av.f * (g2i + g1[j]);   // adj value is exactly 1.0
                    float lr = s > 0.f ? s : 0.2f * s; // leaky_relu(0.2)
                    int pos = atomicAdd(&cnt, 1);
                    if (pos < CAP) { eidx[pos] = j; ev[pos] = lr; }
                }
            }
        }
    }
    __syncthreads();
    const int K = cnt < CAP ? cnt : CAP;

    if (K == 0) {
        // softmax over all -9e15 -> uniform 1/N -> column mean of h
        float acc = 0.f;
        for (int j = 0; j < N_NODES; ++j) acc += bf2f(h[(size_t)j * DOUT + tid]);
        out[(size_t)i * DOUT + tid] = acc / (float)N_NODES;
        return;
    }

    // row max
    float mloc = -1e30f;
    for (int k = tid; k < K; k += 256) mloc = fmaxf(mloc, ev[k]);
    red[tid] = mloc; __syncthreads();
    for (int s = 128; s > 0; s >>= 1) {
        if (tid < s) red[tid] = fmaxf(red[tid], red[tid + s]);
        __syncthreads();
    }
    const float m = red[0];
    __syncthreads();

    // exp + sum
    float sloc = 0.f;
    for (int k = tid; k < K; k += 256) { float p = expf(ev[k] - m); ev[k] = p; sloc += p; }
    red[tid] = sloc; __syncthreads();
    for (int s = 128; s > 0; s >>= 1) {
        if (tid < s) red[tid] += red[tid + s];
        __syncthreads();
    }
    const float inv = 1.f / red[0];

    // out[i, d=tid] = (1/S) * sum_k p_k * h[j_k][d]  (h reads coalesced across lanes)
    float acc = 0.f;
    for (int k = 0; k < K; ++k) acc += ev[k] * bf2f(h[(size_t)eidx[k] * DOUT + tid]);
    out[(size_t)i * DOUT + tid] = acc * inv;
}

extern "C" void kernel_launch(void* const* d_in, const int* in_sizes, int n_in,
                              void* d_out, int out_size, void* d_ws, size_t ws_size,
                              hipStream_t stream) {
    const float* x   = (const float*)d_in[0];  // [8192,512] fp32
    const float* adj = (const float*)d_in[1];  // [8192,8192] fp32
    const float* W1  = (const float*)d_in[2];  // [512,256] fp32
    const float* b1  = (const float*)d_in[3];  // [256] fp32
    const float* a1w = (const float*)d_in[4];  // [256] fp32
    const float* a1b = (const float*)d_in[5];  // [1] fp32
    const float* a2w = (const float*)d_in[6];  // [256] fp32
    const float* a2b = (const float*)d_in[7];  // [1] fp32

    // ws layout: g1 fp32[8192] | g2 fp32[8192] | h bf16[8192*256]   (~4.26 MB)
    float* g1 = (float*)d_ws;
    float* g2 = g1 + N_NODES;
    unsigned short* h = (unsigned short*)(g2 + N_NODES);
    float* out = (float*)d_out;                 // [8192,256] fp32

    hipLaunchKernelGGL(gemm_h_kernel, dim3(512),  dim3(256), 0, stream, x, W1, b1, h);
    hipLaunchKernelGGL(g12_kernel,    dim3(2048), dim3(256), 0, stream, h, a1w, a1b, a2w, a2b, g1, g2);
    hipLaunchKernelGGL(agg_kernel,    dim3(8192), dim3(256), 0, stream, adj, h, g1, g2, out);
}

// Round 6
// 423.979 us; speedup vs baseline: 1.3036x; 1.3036x over previous
//
#include <hip/hip_runtime.h>
#include <hip/hip_bf16.h>
#include <cstdint>
#include <cstddef>

#define N_NODES 8192
#define DIN 512
#define DOUT 256
#define CAP 512   // max edges/row buffered; Binom(8192,0.004): mean 32.8, sd 5.7

typedef short bf16x8 __attribute__((ext_vector_type(8)));
typedef float f32x4 __attribute__((ext_vector_type(4)));
typedef unsigned int u32x4 __attribute__((ext_vector_type(4)));

__device__ __forceinline__ float bf2f(unsigned short u) {
    union { unsigned int ui; float f; } v; v.ui = ((unsigned int)u) << 16; return v.f;
}
__device__ __forceinline__ unsigned short f2bf(float f) {
    union { float f; unsigned int u; } v; v.f = f;
    unsigned int u = v.u;
    return (unsigned short)((u + 0x7fffu + ((u >> 16) & 1u)) >> 16);  // RNE
}
__device__ __forceinline__ float elu1(float v) { return v > 0.f ? v : (expf(v) - 1.f); }

// -------- kernel 1: h = elu(x) @ W1 + b1   [8192,512]fp32 x [512,256]fp32 -> bf16 h --------
// block tile 64 rows x 64 cols; wave computes 4 m-subtiles of 16x16 (B frag reused 4x)
// mfma_f32_16x16x32_bf16: A[m=lane&15][k=quad*8+j], B[k=quad*8+j][n=lane&15],
// D[row=quad*4+r][col=lane&15]
__global__ __launch_bounds__(256) void gemm_h_kernel(
    const float* __restrict__ x, const float* __restrict__ W1,
    const float* __restrict__ b1, unsigned short* __restrict__ h)
{
    const int tid = threadIdx.x;
    const int wave = tid >> 6, lane = tid & 63;
    const int quad = lane >> 4, r16 = lane & 15;
    const int m0 = (blockIdx.x >> 2) * 64;                 // 128 m-blocks
    const int col = (blockIdx.x & 3) * 64 + wave * 16 + r16;

    f32x4 acc[4] = {{0.f,0.f,0.f,0.f},{0.f,0.f,0.f,0.f},{0.f,0.f,0.f,0.f},{0.f,0.f,0.f,0.f}};

    for (int k0 = 0; k0 < DIN; k0 += 32) {
        const int kbase = k0 + quad * 8;
        bf16x8 bfr;
        #pragma unroll
        for (int j = 0; j < 8; ++j)
            bfr[j] = (short)f2bf(W1[(size_t)(kbase + j) * DOUT + col]);
        #pragma unroll
        for (int r = 0; r < 4; ++r) {
            const float* xrow = x + (size_t)(m0 + r * 16 + r16) * DIN;
            float4 f0 = *(const float4*)(xrow + kbase);
            float4 f1 = *(const float4*)(xrow + kbase + 4);
            bf16x8 af;
            af[0] = (short)f2bf(elu1(f0.x)); af[1] = (short)f2bf(elu1(f0.y));
            af[2] = (short)f2bf(elu1(f0.z)); af[3] = (short)f2bf(elu1(f0.w));
            af[4] = (short)f2bf(elu1(f1.x)); af[5] = (short)f2bf(elu1(f1.y));
            af[6] = (short)f2bf(elu1(f1.z)); af[7] = (short)f2bf(elu1(f1.w));
            acc[r] = __builtin_amdgcn_mfma_f32_16x16x32_bf16(af, bfr, acc[r], 0, 0, 0);
        }
    }
    const float bias = b1[col];
    #pragma unroll
    for (int r = 0; r < 4; ++r)
        #pragma unroll
        for (int rr = 0; rr < 4; ++rr)
            h[(size_t)(m0 + r * 16 + quad * 4 + rr) * DOUT + col] = f2bf(acc[r][rr] + bias);
}

// -------- kernel 2: g1 = h@a1_w + a1_b, g2 = h@a2_w + a2_b  (wave per row) --------
__global__ __launch_bounds__(256) void g12_kernel(
    const unsigned short* __restrict__ h,
    const float* __restrict__ a1w, const float* __restrict__ a1b,
    const float* __restrict__ a2w, const float* __restrict__ a2b,
    float* __restrict__ g1, float* __restrict__ g2)
{
    const int tid = threadIdx.x;
    const int wave = tid >> 6, lane = tid & 63;
    const int i = blockIdx.x * 4 + wave;
    const int d0 = lane * 4;
    ushort4 hv = *(const ushort4*)(h + (size_t)i * DOUT + d0);
    float4 w1 = *(const float4*)(a1w + d0);
    float4 w2 = *(const float4*)(a2w + d0);
    float h0 = bf2f(hv.x), h1 = bf2f(hv.y), h2 = bf2f(hv.z), h3 = bf2f(hv.w);
    float s1 = h0*w1.x + h1*w1.y + h2*w1.z + h3*w1.w;
    float s2 = h0*w2.x + h1*w2.y + h2*w2.z + h3*w2.w;
    #pragma unroll
    for (int off = 32; off > 0; off >>= 1) {
        s1 += __shfl_xor(s1, off, 64);
        s2 += __shfl_xor(s2, off, 64);
    }
    if (lane == 0) {
        g1[i] = s1 + a1b[0];
        g2[i] = s2 + a2b[0];
    }
}

// -------- kernel 3: per-row masked softmax + aggregation (block per row) --------
// Scan layout: iter c covers cols [c*1024, c*1024+1024); thread t takes 4 floats at
// c*1024 + t*4 -> each wave instr = 64 lanes x 16 B CONTIGUOUS (1 KB), every fetched
// line fully consumed immediately (fixes the 2.9x L2-thrash over-fetch of round 4).
__global__ __launch_bounds__(256) void agg_kernel(
    const float* __restrict__ adj, const unsigned short* __restrict__ h,
    const float* __restrict__ g1, const float* __restrict__ g2,
    float* __restrict__ out)
{
    __shared__ int   eidx[CAP];
    __shared__ float ev[CAP];
    __shared__ float red[256];
    __shared__ int   cnt;

    const int tid = threadIdx.x;
    const int i = blockIdx.x;
    if (tid == 0) cnt = 0;
    __syncthreads();

    const float g2i = g2[i];
    const float* arow = adj + (size_t)i * N_NODES;

    // prefetch all 8 streaming loads (nontemporal: adj has zero reuse)
    u32x4 raws[8];
    #pragma unroll
    for (int c = 0; c < 8; ++c)
        raws[c] = __builtin_nontemporal_load((const u32x4*)(arow + c * 1024 + tid * 4));

    #pragma unroll
    for (int c = 0; c < 8; ++c) {
        u32x4 raw = raws[c];
        if (raw.x | raw.y | raw.z | raw.w) {
            unsigned int wv[4] = {raw.x, raw.y, raw.z, raw.w};
            #pragma unroll
            for (int q = 0; q < 4; ++q) {
                if (wv[q]) {
                    int j = c * 1024 + tid * 4 + q;
                    union { unsigned int u; float f; } av; av.u = wv[q];
                    float s = av.f * (g2i + g1[j]);    // adj value is exactly 1.0
                    float lr = s > 0.f ? s : 0.2f * s; // leaky_relu(0.2)
                    int pos = atomicAdd(&cnt, 1);
                    if (pos < CAP) { eidx[pos] = j; ev[pos] = lr; }
                }
            }
        }
    }
    __syncthreads();
    const int K = cnt < CAP ? cnt : CAP;

    if (K == 0) {
        // softmax over all -9e15 -> uniform 1/N -> column mean of h
        float acc = 0.f;
        for (int j = 0; j < N_NODES; ++j) acc += bf2f(h[(size_t)j * DOUT + tid]);
        out[(size_t)i * DOUT + tid] = acc / (float)N_NODES;
        return;
    }

    // row max
    float mloc = -1e30f;
    for (int k = tid; k < K; k += 256) mloc = fmaxf(mloc, ev[k]);
    red[tid] = mloc; __syncthreads();
    for (int s = 128; s > 0; s >>= 1) {
        if (tid < s) red[tid] = fmaxf(red[tid], red[tid + s]);
        __syncthreads();
    }
    const float m = red[0];
    __syncthreads();

    // exp + sum
    float sloc = 0.f;
    for (int k = tid; k < K; k += 256) { float p = expf(ev[k] - m); ev[k] = p; sloc += p; }
    red[tid] = sloc; __syncthreads();
    for (int s = 128; s > 0; s >>= 1) {
        if (tid < s) red[tid] += red[tid + s];
        __syncthreads();
    }
    const float inv = 1.f / red[0];

    // out[i, d=tid] = (1/S) * sum_k p_k * h[j_k][d]  (coalesced across lanes; 4-way MLP)
    float acc = 0.f;
    int k = 0;
    for (; k + 4 <= K; k += 4) {
        float p0 = ev[k],     p1 = ev[k + 1], p2 = ev[k + 2], p3 = ev[k + 3];
        int   j0 = eidx[k],   j1 = eidx[k+1], j2 = eidx[k+2], j3 = eidx[k+3];
        float v0 = bf2f(h[(size_t)j0 * DOUT + tid]);
        float v1 = bf2f(h[(size_t)j1 * DOUT + tid]);
        float v2 = bf2f(h[(size_t)j2 * DOUT + tid]);
        float v3 = bf2f(h[(size_t)j3 * DOUT + tid]);
        acc += p0 * v0 + p1 * v1 + p2 * v2 + p3 * v3;
    }
    for (; k < K; ++k) acc += ev[k] * bf2f(h[(size_t)eidx[k] * DOUT + tid]);
    out[(size_t)i * DOUT + tid] = acc * inv;
}

extern "C" void kernel_launch(void* const* d_in, const int* in_sizes, int n_in,
                              void* d_out, int out_size, void* d_ws, size_t ws_size,
                              hipStream_t stream) {
    const float* x   = (const float*)d_in[0];  // [8192,512] fp32
    const float* adj = (const float*)d_in[1];  // [8192,8192] fp32
    const float* W1  = (const float*)d_in[2];  // [512,256] fp32
    const float* b1  = (const float*)d_in[3];  // [256] fp32
    const float* a1w = (const float*)d_in[4];  // [256] fp32
    const float* a1b = (const float*)d_in[5];  // [1] fp32
    const float* a2w = (const float*)d_in[6];  // [256] fp32
    const float* a2b = (const float*)d_in[7];  // [1] fp32

    // ws layout: g1 fp32[8192] | g2 fp32[8192] | h bf16[8192*256]   (~4.26 MB)
    float* g1 = (float*)d_ws;
    float* g2 = g1 + N_NODES;
    unsigned short* h = (unsigned short*)(g2 + N_NODES);
    float* out = (float*)d_out;                 // [8192,256] fp32

    hipLaunchKernelGGL(gemm_h_kernel, dim3(512),  dim3(256), 0, stream, x, W1, b1, h);
    hipLaunchKernelGGL(g12_kernel,    dim3(2048), dim3(256), 0, stream, h, a1w, a1b, a2w, a2b, g1, g2);
    hipLaunchKernelGGL(agg_kernel,    dim3(8192), dim3(256), 0, stream, adj, h, g1, g2, out);
}